// Round 6
// baseline (119.573 us; speedup 1.0000x reference)
//
#include <hip/hip_runtime.h>

#define NPIX 409600   // 640*640
#define NB 8          // batch

// ---------------- workspace layout (4-byte words, per batch) ----------------
constexpr int OFF_H0    = 0;     // 2048 u32  level-0 histogram (key bits 31..21)
constexpr int OFF_H1    = 2048;  // 2048 u32  (fallback path only)
constexpr int OFF_H2    = 4096;  // 1024 u32  (fallback path only)
constexpr int OFF_KC    = 5120;  // 8 u32     kernel-mask counts per instance
constexpr int OFF_TC    = 5128;  // 8 u32     text-mask counts per instance
constexpr int OFF_KS    = 5136;  // 32 f32    kernel-mask sim sums (inst*4+c)
constexpr int OFF_AGG   = 5168;  // 8 f32     per-instance sum log1p(D)
constexpr int OFF_CPOS  = 5176;  // u32
constexpr int OFF_CPOSM = 5177;  // u32  pos & tm<=0.5
constexpr int OFF_NEGNUM= 5179;  // u32
constexpr int OFF_PFX0  = 5180;  // u32
constexpr int OFF_K1    = 5181;  // u32
constexpr int OFF_PFX1  = 5182;  // u32
constexpr int OFF_K2    = 5183;  // u32
constexpr int OFF_TH    = 5184;  // f32  OHEM threshold
constexpr int OFF_FALL  = 5185;  // u32  fallback flag
constexpr int OFF_G     = 5186;  // 32 f32 centroids
constexpr int OFF_NV    = 5218;  // u32 n_valid
constexpr int OFF_VM    = 5219;  // u32 valid bitmask
constexpr int OFF_LDIS  = 5220;  // f32
constexpr int OFF_DICE  = 5221;  // 6 f32: at,bt,ct,ak,bk,ck
constexpr int OFF_KN    = 5227;  // u32 compact key count
constexpr int PER_BATCH = 5376;  // padded
constexpr int KEYS_BASE = NB * PER_BATCH;  // compact key arrays (words)
constexpr int HDR_WORDS = NB * PER_BATCH;  // 43008 words = 168 KB

__device__ __forceinline__ unsigned mapf(float s) {
  unsigned b = __float_as_uint(s);
  return (b & 0x80000000u) ? ~b : (b | 0x80000000u);
}
__device__ __forceinline__ float unmapf(unsigned u) {
  return __uint_as_float((u & 0x80000000u) ? (u & 0x7FFFFFFFu) : ~u);
}

__device__ __forceinline__ float wredf(float v) {
#pragma unroll
  for (int m = 32; m >= 1; m >>= 1) v += __shfl_xor(v, m, 64);
  return v;
}
__device__ __forceinline__ unsigned wredu(unsigned v) {
#pragma unroll
  for (int m = 32; m >= 1; m >>= 1) v += (unsigned)__shfl_xor((int)v, m, 64);
  return v;
}

// ---- pass Z: zero the workspace header --------------------------------------
__global__ __launch_bounds__(256) void kZ(unsigned* __restrict__ ws) {
  int i = blockIdx.x * 256 + threadIdx.x;
  if (i < HDR_WORDS) ws[i] = 0u;
}

// ---- pass P1: fused stats. hist0 + cpos/cposm + tc/kc + ks sums +
//               kernel-dice sums + register-resident key compaction ----------
template <bool COMPACT>
__global__ __launch_bounds__(256) void kP1(const float* __restrict__ out_,
                                           const int* __restrict__ lab_,
                                           const float* __restrict__ tm_,
                                           unsigned* __restrict__ ws) {
  const int b = blockIdx.y;
  unsigned* wsb = ws + (size_t)b * PER_BATCH;
  float* wsbf = (float*)wsb;
  __shared__ unsigned sh_h[2048];                  // 8 KB
  __shared__ __align__(16) float L[8 * 257 * 4];   // 32.9 KB private ks slots
  __shared__ float L2[32 * 8];
  __shared__ unsigned sh_scan[256];
  __shared__ unsigned sh_tcw[4 * 7], sh_kcw[4 * 7];
  __shared__ float sKD[4 * 3];
  __shared__ unsigned sh_c[2];
  __shared__ unsigned sh_base;
  const int tid = threadIdx.x;
  const int lane = tid & 63;
  const int w = tid >> 6;
  for (int i = tid; i < 2048; i += 256) sh_h[i] = 0u;
  for (int i = tid; i < 8 * 257 * 4; i += 256) L[i] = 0.f;
  if (tid < 2) sh_c[tid] = 0u;
  __syncthreads();

  const float4* tx = (const float4*)(out_ + (size_t)b * 6 * NPIX);
  const float4* kr = (const float4*)(out_ + (size_t)b * 6 * NPIX + (size_t)NPIX);
  const float4* s0 = (const float4*)(out_ + (size_t)b * 6 * NPIX + 2 * (size_t)NPIX);
  const float4* s1 = (const float4*)(out_ + (size_t)b * 6 * NPIX + 3 * (size_t)NPIX);
  const float4* s2 = (const float4*)(out_ + (size_t)b * 6 * NPIX + 4 * (size_t)NPIX);
  const float4* s3 = (const float4*)(out_ + (size_t)b * 6 * NPIX + 5 * (size_t)NPIX);
  const int4* gt = (const int4*)(lab_ + (size_t)b * 2 * NPIX);
  const int4* gk = (const int4*)(lab_ + (size_t)b * 2 * NPIX + NPIX);
  const float4* tmv = (const float4*)(tm_ + (size_t)b * NPIX);

  unsigned cpos = 0, cposm = 0;
  unsigned tcq[7], kcq[7];
#pragma unroll
  for (int k = 0; k < 7; ++k) { tcq[k] = 0u; kcq[k] = 0u; }
  unsigned kreg[8];
  unsigned vmask = 0;
  float ak = 0.f, bk = 0.f, ck = 0.f;

  // grid.x = 200 -> 51200 threads/batch, exactly 2 quad-iters each
#pragma unroll
  for (int it = 0; it < 2; ++it) {
    const int i = it * 51200 + blockIdx.x * 256 + tid;
    float4 t4 = tx[i]; int4 g4 = gt[i]; int4 k4 = gk[i];
    float4 m4 = tmv[i]; float4 q4 = kr[i];
    float4 a0 = s0[i], a1 = s1[i], a2 = s2[i], a3 = s3[i];
#pragma unroll
    for (int j = 0; j < 4; ++j) {
      float tv = ((const float*)&t4)[j];
      int gtv = ((const int*)&g4)[j];
      int gkv = ((const int*)&k4)[j];
      float mv = ((const float*)&m4)[j];
      float kv = ((const float*)&q4)[j];
      bool pos = gtv > 0;
      cpos += pos;
      cposm += (pos && (mv <= 0.5f));
      unsigned key = mapf(tv);
      kreg[it * 4 + j] = key;
      if (!pos) {
        vmask |= (1u << (it * 4 + j));
        atomicAdd(&sh_h[key >> 21], 1u);
      }
#pragma unroll
      for (int k = 0; k < 7; ++k) {
        tcq[k] += (unsigned)__popcll(__ballot(gtv == k + 1));
        kcq[k] += (unsigned)__popcll(__ballot(gkv == k + 1));
      }
      // per-instance sim sums into private LDS slot (idx 7 = trash)
      int idx = (gkv > 0) ? (gkv - 1) : 7;
      float4* slot = (float4*)&L[(idx * 257 + tid) * 4];
      float4 rr = *slot;
      rr.x += ((const float*)&a0)[j];
      rr.y += ((const float*)&a1)[j];
      rr.z += ((const float*)&a2)[j];
      rr.w += ((const float*)&a3)[j];
      *slot = rr;
      // kernel-dice (threshold-independent): selk = sigmoid(tv)>0.5 & tm>0.5
      float selk = ((tv > 0.f) && (mv > 0.5f)) ? 1.f : 0.f;
      float pk = selk / (1.f + expf(-kv));
      float tk = (gkv > 0) ? selk : 0.f;
      ak += pk * tk; bk += pk * pk; ck += tk * tk;
    }
  }

  // wave-level partials
  unsigned r;
  r = wredu(cpos);  if (lane == 0) atomicAdd(&sh_c[0], r);
  r = wredu(cposm); if (lane == 0) atomicAdd(&sh_c[1], r);
  if (lane == 0) {
#pragma unroll
    for (int k = 0; k < 7; ++k) { sh_tcw[w * 7 + k] = tcq[k]; sh_kcw[w * 7 + k] = kcq[k]; }
  }
  float f;
  f = wredf(ak); if (lane == 0) sKD[w * 3 + 0] = f;
  f = wredf(bk); if (lane == 0) sKD[w * 3 + 1] = f;
  f = wredf(ck); if (lane == 0) sKD[w * 3 + 2] = f;

  // block scan of per-thread neg counts (for compaction)
  unsigned cnt = (unsigned)__popc(vmask);
  sh_scan[tid] = cnt;
  __syncthreads();
#pragma unroll
  for (int off = 1; off < 256; off <<= 1) {
    unsigned v = (tid >= off) ? sh_scan[tid - off] : 0u;
    __syncthreads();
    sh_scan[tid] += v;
    __syncthreads();
  }
  if (COMPACT && tid == 0) sh_base = atomicAdd(&wsb[OFF_KN], sh_scan[255]);

  // ks reduce stage 1: [8 idx][256 tid][4 c] -> L2[32 planes][8 subs]
  {
    int p = tid & 31, sub = tid >> 5;
    int idx = p & 7, c = p >> 3;
    float part = 0.f;
#pragma unroll
    for (int i = 0; i < 32; ++i) part += L[(idx * 257 + (sub + 8 * i)) * 4 + c];
    L2[p * 8 + sub] = part;
  }
  // flush hist + counters
  for (int i = tid; i < 2048; i += 256) {
    unsigned v = sh_h[i]; if (v) atomicAdd(&wsb[OFF_H0 + i], v);
  }
  if (tid < 7) {
    unsigned s = sh_tcw[tid] + sh_tcw[7 + tid] + sh_tcw[14 + tid] + sh_tcw[21 + tid];
    if (s) atomicAdd(&wsb[OFF_TC + 1 + tid], s);
  } else if (tid < 14) {
    int k = tid - 7;
    unsigned s = sh_kcw[k] + sh_kcw[7 + k] + sh_kcw[14 + k] + sh_kcw[21 + k];
    if (s) atomicAdd(&wsb[OFF_KC + 1 + k], s);
  } else if (tid >= 16 && tid < 19) {
    int c = tid - 16;
    float s = sKD[c] + sKD[3 + c] + sKD[6 + c] + sKD[9 + c];
    atomicAdd(&wsbf[OFF_DICE + 3 + c], s);
  }
  if (tid == 0) {
    atomicAdd(&wsb[OFF_CPOS], sh_c[0]);
    atomicAdd(&wsb[OFF_CPOSM], sh_c[1]);
  }
  __syncthreads();   // L2 + sh_base ready
  if (tid < 32) {
    float s = 0.f;
#pragma unroll
    for (int q = 0; q < 8; ++q) s += L2[tid * 8 + q];
    int idx = tid & 7, c = tid >> 3;
    if (idx < 7 && s != 0.f) atomicAdd(&wsbf[OFF_KS + (idx + 1) * 4 + c], s);
  }
  if (COMPACT) {
    unsigned gb = sh_base + sh_scan[tid] - cnt;
    unsigned* keys = ws + KEYS_BASE + (size_t)b * NPIX;
#pragma unroll
    for (int s = 0; s < 8; ++s) {
      if (vmask & (1u << s)) { keys[gb] = kreg[s]; ++gb; }
    }
  }
}

// ---- pass Sel: one block per batch. scalar prologue + full 3-level radix
//      select (L0 from global hist, L1/L2 from compact key list) -------------
__global__ __launch_bounds__(1024) void kSel(unsigned* __restrict__ ws) {
  const int b = blockIdx.x;
  unsigned* wsb = ws + (size_t)b * PER_BATCH;
  float* wsbf = (float*)wsb;
  __shared__ unsigned H[2048];
  __shared__ unsigned S[256];
  __shared__ unsigned sh_pfx0, sh_pfx1, sh_k;
  __shared__ int sh_fall;
  const int tid = threadIdx.x;

  if (tid == 0) {
    long cpos = (long)wsb[OFF_CPOS], cposm = (long)wsb[OFF_CPOSM];
    long cneg = (long)NPIX - cpos;
    long posnum = cpos - cposm;
    long negnum = posnum * 3; if (negnum > cneg) negnum = cneg;
    int fall = (posnum == 0) || (negnum == 0);
    wsb[OFF_NEGNUM] = (unsigned)negnum;
    wsb[OFF_FALL] = (unsigned)fall;
    sh_fall = fall; sh_k = (unsigned)negnum;
    wsbf[OFF_TH] = 0.f;
    unsigned nvv = 0, vmask = 0;
    for (int k = 1; k < 8; ++k) {
      unsigned kc = wsb[OFF_KC + k], tc = wsb[OFF_TC + k];
      float inv = 1.f / fmaxf((float)kc, 1.f);
      for (int c = 0; c < 4; ++c) wsbf[OFF_G + k * 4 + c] = wsbf[OFF_KS + k * 4 + c] * inv;
      if (kc > 0 && tc > 0) { vmask |= (1u << k); ++nvv; }
    }
    wsb[OFF_NV] = nvv; wsb[OFF_VM] = vmask;
    float s = 0.f;
    for (int i = 1; i < 8; ++i) {
      if (!((vmask >> i) & 1)) continue;
      for (int j = i + 1; j < 8; ++j) {
        if (!((vmask >> j) & 1)) continue;
        float sq = 0.f;
        for (int c = 0; c < 4; ++c) {
          float d = wsbf[OFF_G + i * 4 + c] - wsbf[OFF_G + j * 4 + c];
          sq += d * d;
        }
        float gn = (sq > 0.f) ? sqrtf(sq) : 0.f;
        float dd = fmaxf(3.0f - gn, 0.f);
        s += log1pf(dd * dd);
      }
    }
    float denom = (float)(nvv * (nvv > 0 ? nvv - 1u : 0u));
    wsbf[OFF_LDIS] = (nvv > 1) ? (s / fmaxf(denom, 1.f)) : 0.f;
  }
  __syncthreads();
  if (sh_fall) return;
  const unsigned kn = wsb[OFF_KN];
  const unsigned* keys = ws + KEYS_BASE + (size_t)b * NPIX;

  // ---------- level 0: from global H0 ----------
  unsigned myp = 0;
  if (tid < 256) {
#pragma unroll
    for (int j = 0; j < 8; ++j) myp += wsb[OFF_H0 + tid * 8 + j];
    S[tid] = myp;
  }
  __syncthreads();
#pragma unroll
  for (int off = 1; off < 256; off <<= 1) {
    unsigned v = 0;
    if (tid < 256 && tid + off < 256) v = S[tid + off];
    __syncthreads();
    if (tid < 256) S[tid] += v;
    __syncthreads();
  }
  {
    unsigned k = sh_k;
    __syncthreads();
    if (tid < 256) {
      unsigned suf = S[tid], sufn = suf - myp;
      if (suf >= k && sufn < k) {
        unsigned kk = k - sufn;
        unsigned cum2 = 0; int bin = tid * 8;
#pragma unroll
        for (int j = 7; j >= 0; --j) {
          unsigned h = wsb[OFF_H0 + tid * 8 + j]; cum2 += h;
          if (cum2 >= kk) { bin = tid * 8 + j; kk -= (cum2 - h); break; }
        }
        sh_pfx0 = (unsigned)bin; sh_k = kk;
      }
    }
  }
  __syncthreads();
  const unsigned pfx0 = sh_pfx0;

  // ---------- level 1: scan compact keys ----------
  for (int i = tid; i < 2048; i += 1024) H[i] = 0u;
  __syncthreads();
  for (unsigned i = tid; i < kn; i += 1024) {
    unsigned key = keys[i];
    if ((key >> 21) == pfx0) atomicAdd(&H[(key >> 10) & 0x7FFu], 1u);
  }
  __syncthreads();
  myp = 0;
  if (tid < 256) {
#pragma unroll
    for (int j = 0; j < 8; ++j) myp += H[tid * 8 + j];
    S[tid] = myp;
  }
  __syncthreads();
#pragma unroll
  for (int off = 1; off < 256; off <<= 1) {
    unsigned v = 0;
    if (tid < 256 && tid + off < 256) v = S[tid + off];
    __syncthreads();
    if (tid < 256) S[tid] += v;
    __syncthreads();
  }
  {
    unsigned k = sh_k;
    __syncthreads();
    if (tid < 256) {
      unsigned suf = S[tid], sufn = suf - myp;
      if (suf >= k && sufn < k) {
        unsigned kk = k - sufn;
        unsigned cum2 = 0; int bin = tid * 8;
#pragma unroll
        for (int j = 7; j >= 0; --j) {
          unsigned h = H[tid * 8 + j]; cum2 += h;
          if (cum2 >= kk) { bin = tid * 8 + j; kk -= (cum2 - h); break; }
        }
        sh_pfx1 = (unsigned)bin; sh_k = kk;
      }
    }
  }
  __syncthreads();
  const unsigned pfx22 = (pfx0 << 11) | sh_pfx1;

  // ---------- level 2 ----------
  if (tid < 1024) H[tid] = 0u;
  __syncthreads();
  for (unsigned i = tid; i < kn; i += 1024) {
    unsigned key = keys[i];
    if ((key >> 10) == pfx22) atomicAdd(&H[key & 0x3FFu], 1u);
  }
  __syncthreads();
  myp = 0;
  if (tid < 256) {
#pragma unroll
    for (int j = 0; j < 4; ++j) myp += H[tid * 4 + j];
    S[tid] = myp;
  }
  __syncthreads();
#pragma unroll
  for (int off = 1; off < 256; off <<= 1) {
    unsigned v = 0;
    if (tid < 256 && tid + off < 256) v = S[tid + off];
    __syncthreads();
    if (tid < 256) S[tid] += v;
    __syncthreads();
  }
  {
    unsigned k = sh_k;
    __syncthreads();
    if (tid < 256) {
      unsigned suf = S[tid], sufn = suf - myp;
      if (suf >= k && sufn < k) {
        unsigned kk = k - sufn;
        unsigned cum2 = 0; int bin = tid * 4;
#pragma unroll
        for (int j = 3; j >= 0; --j) {
          unsigned h = H[tid * 4 + j]; cum2 += h;
          if (cum2 >= kk) { bin = tid * 4 + j; break; }
        }
        unsigned key = (pfx22 << 10) | (unsigned)bin;
        wsbf[OFF_TH] = unmapf(key);
      }
    }
  }
}

// ------- fallback-only kernels (no compact keys available) -------------------
__global__ void kB(unsigned* __restrict__ ws) {
  const int b = blockIdx.x;
  unsigned* wsb = ws + (size_t)b * PER_BATCH;
  float* wsbf = (float*)wsb;
  __shared__ unsigned S[256];
  __shared__ unsigned sh_k;
  __shared__ int sh_fall;
  const int tid = threadIdx.x;
  if (tid == 0) {
    long cpos = (long)wsb[OFF_CPOS], cposm = (long)wsb[OFF_CPOSM];
    long cneg = (long)NPIX - cpos;
    long posnum = cpos - cposm;
    long negnum = posnum * 3; if (negnum > cneg) negnum = cneg;
    int fall = (posnum == 0) || (negnum == 0);
    wsb[OFF_NEGNUM] = (unsigned)negnum;
    wsb[OFF_FALL] = (unsigned)fall;
    sh_k = (unsigned)negnum; sh_fall = fall;
    unsigned nvv = 0, vmask = 0;
    for (int k = 1; k < 8; ++k) {
      unsigned kc = wsb[OFF_KC + k], tc = wsb[OFF_TC + k];
      float inv = 1.f / fmaxf((float)kc, 1.f);
      for (int c = 0; c < 4; ++c) wsbf[OFF_G + k * 4 + c] = wsbf[OFF_KS + k * 4 + c] * inv;
      if (kc > 0 && tc > 0) { vmask |= (1u << k); ++nvv; }
    }
    wsb[OFF_NV] = nvv; wsb[OFF_VM] = vmask;
    float s = 0.f;
    for (int i = 1; i < 8; ++i) {
      if (!((vmask >> i) & 1)) continue;
      for (int j = i + 1; j < 8; ++j) {
        if (!((vmask >> j) & 1)) continue;
        float sq = 0.f;
        for (int c = 0; c < 4; ++c) {
          float d = wsbf[OFF_G + i * 4 + c] - wsbf[OFF_G + j * 4 + c];
          sq += d * d;
        }
        float gn = (sq > 0.f) ? sqrtf(sq) : 0.f;
        float dd = fmaxf(3.0f - gn, 0.f);
        s += log1pf(dd * dd);
      }
    }
    float denom = (float)(nvv * (nvv > 0 ? nvv - 1u : 0u));
    wsbf[OFF_LDIS] = (nvv > 1) ? (s / fmaxf(denom, 1.f)) : 0.f;
    if (fall) wsb[OFF_PFX0] = 0xFFFFFFFFu;
  }
  __syncthreads();
  if (sh_fall) return;
  unsigned p = 0;
#pragma unroll
  for (int j = 0; j < 8; ++j) p += wsb[OFF_H0 + tid * 8 + j];
  S[tid] = p;
  __syncthreads();
#pragma unroll
  for (int off = 1; off < 256; off <<= 1) {
    unsigned v = (tid + off < 256) ? S[tid + off] : 0u;
    __syncthreads();
    S[tid] += v;
    __syncthreads();
  }
  unsigned k = sh_k;
  unsigned suf = S[tid];
  unsigned sufn = suf - p;
  if (suf >= k && sufn < k) {
    unsigned kk = k - sufn;
    unsigned cum2 = 0; int bin = tid * 8;
    for (int j = 7; j >= 0; --j) {
      unsigned h = wsb[OFF_H0 + tid * 8 + j]; cum2 += h;
      if (cum2 >= kk) { bin = tid * 8 + j; kk -= (cum2 - h); break; }
    }
    wsb[OFF_PFX0] = (unsigned)bin;
    wsb[OFF_K1] = kk;
  }
}

__global__ __launch_bounds__(256) void kC(const float* __restrict__ out_,
                                          const int* __restrict__ lab_,
                                          unsigned* __restrict__ ws) {
  const int b = blockIdx.y;
  unsigned* wsb = ws + (size_t)b * PER_BATCH;
  if (wsb[OFF_FALL]) return;
  const unsigned pfx = wsb[OFF_PFX0];
  __shared__ unsigned sh_h[2048];
  for (int i = threadIdx.x; i < 2048; i += 256) sh_h[i] = 0u;
  __syncthreads();
  const float4* tx = (const float4*)(out_ + (size_t)b * 6 * NPIX);
  const int4* gt = (const int4*)(lab_ + (size_t)b * 2 * NPIX);
  const int nv = NPIX / 4;
  for (int i = blockIdx.x * blockDim.x + threadIdx.x; i < nv; i += gridDim.x * blockDim.x) {
    float4 t4 = tx[i]; int4 g4 = gt[i];
#pragma unroll
    for (int j = 0; j < 4; ++j) {
      if (((const int*)&g4)[j] <= 0) {
        unsigned key = mapf(((const float*)&t4)[j]);
        if ((key >> 21) == pfx) atomicAdd(&sh_h[(key >> 10) & 0x7FFu], 1u);
      }
    }
  }
  __syncthreads();
  for (int i = threadIdx.x; i < 2048; i += 256) {
    unsigned v = sh_h[i]; if (v) atomicAdd(&wsb[OFF_H1 + i], v);
  }
}

__global__ void kD(unsigned* __restrict__ ws) {
  const int b = blockIdx.x;
  unsigned* wsb = ws + (size_t)b * PER_BATCH;
  if (wsb[OFF_FALL]) return;
  __shared__ unsigned S[256];
  const int tid = threadIdx.x;
  unsigned p = 0;
#pragma unroll
  for (int j = 0; j < 8; ++j) p += wsb[OFF_H1 + tid * 8 + j];
  S[tid] = p;
  __syncthreads();
#pragma unroll
  for (int off = 1; off < 256; off <<= 1) {
    unsigned v = (tid + off < 256) ? S[tid + off] : 0u;
    __syncthreads();
    S[tid] += v;
    __syncthreads();
  }
  unsigned k = wsb[OFF_K1];
  unsigned suf = S[tid];
  unsigned sufn = suf - p;
  if (suf >= k && sufn < k) {
    unsigned kk = k - sufn;
    unsigned cum2 = 0; int bin = tid * 8;
    for (int j = 7; j >= 0; --j) {
      unsigned h = wsb[OFF_H1 + tid * 8 + j]; cum2 += h;
      if (cum2 >= kk) { bin = tid * 8 + j; kk -= (cum2 - h); break; }
    }
    wsb[OFF_PFX1] = (unsigned)bin;
    wsb[OFF_K2] = kk;
  }
}

__global__ __launch_bounds__(256) void kE(const float* __restrict__ out_,
                                          const int* __restrict__ lab_,
                                          unsigned* __restrict__ ws) {
  const int b = blockIdx.y;
  unsigned* wsb = ws + (size_t)b * PER_BATCH;
  if (wsb[OFF_FALL]) return;
  const unsigned pfx22 = (wsb[OFF_PFX0] << 11) | wsb[OFF_PFX1];
  __shared__ unsigned sh_h[1024];
  for (int i = threadIdx.x; i < 1024; i += 256) sh_h[i] = 0u;
  __syncthreads();
  const float4* tx = (const float4*)(out_ + (size_t)b * 6 * NPIX);
  const int4* gt = (const int4*)(lab_ + (size_t)b * 2 * NPIX);
  const int nv = NPIX / 4;
  for (int i = blockIdx.x * blockDim.x + threadIdx.x; i < nv; i += gridDim.x * blockDim.x) {
    float4 t4 = tx[i]; int4 g4 = gt[i];
#pragma unroll
    for (int j = 0; j < 4; ++j) {
      if (((const int*)&g4)[j] <= 0) {
        unsigned key = mapf(((const float*)&t4)[j]);
        if ((key >> 10) == pfx22) atomicAdd(&sh_h[key & 0x3FFu], 1u);
      }
    }
  }
  __syncthreads();
  for (int i = threadIdx.x; i < 1024; i += 256) {
    unsigned v = sh_h[i]; if (v) atomicAdd(&wsb[OFF_H2 + i], v);
  }
}

__global__ void kF(unsigned* __restrict__ ws) {
  const int b = blockIdx.x;
  unsigned* wsb = ws + (size_t)b * PER_BATCH;
  float* wsbf = (float*)wsb;
  const int tid = threadIdx.x;
  if (wsb[OFF_FALL]) { if (tid == 0) wsbf[OFF_TH] = 0.f; return; }
  __shared__ unsigned S[256];
  unsigned p = 0;
#pragma unroll
  for (int j = 0; j < 4; ++j) p += wsb[OFF_H2 + tid * 4 + j];
  S[tid] = p;
  __syncthreads();
#pragma unroll
  for (int off = 1; off < 256; off <<= 1) {
    unsigned v = (tid + off < 256) ? S[tid + off] : 0u;
    __syncthreads();
    S[tid] += v;
    __syncthreads();
  }
  unsigned k = wsb[OFF_K2];
  unsigned suf = S[tid];
  unsigned sufn = suf - p;
  if (suf >= k && sufn < k) {
    unsigned kk = k - sufn;
    unsigned cum2 = 0; int bin = tid * 4;
    for (int j = 3; j >= 0; --j) {
      unsigned h = wsb[OFF_H2 + tid * 4 + j]; cum2 += h;
      if (cum2 >= kk) { bin = tid * 4 + j; break; }
    }
    unsigned key = (wsb[OFF_PFX0] << 21) | (wsb[OFF_PFX1] << 10) | (unsigned)bin;
    wsbf[OFF_TH] = unmapf(key);
  }
}

// ---- pass G: agg loss + text-dice sums (7 channels; kernel-dice moved to P1)
__global__ __launch_bounds__(256) void kG(const float* __restrict__ out_,
                                          const int* __restrict__ lab_,
                                          const float* __restrict__ tm_,
                                          unsigned* __restrict__ ws) {
  const int b = blockIdx.y;
  unsigned* wsb = ws + (size_t)b * PER_BATCH;
  float* wsbf = (float*)wsb;
  __shared__ float sG[32];
  __shared__ float LA[8 * 257];
  __shared__ float L2[8 * 33];
  __shared__ float sWred[4 * 3];
  __shared__ float sTh;
  __shared__ int sFall;
  const int tid = threadIdx.x;
  const int lane = tid & 63;
  const int w = tid >> 6;
  if (tid < 32) sG[tid] = wsbf[OFF_G + tid];
  for (int i = tid; i < 8 * 257; i += 256) LA[i] = 0.f;
  if (tid == 0) { sTh = wsbf[OFF_TH]; sFall = (int)wsb[OFF_FALL]; }
  __syncthreads();
  const float th = sTh;
  const int fall = sFall;

  const float4* tx = (const float4*)(out_ + (size_t)b * 6 * NPIX);
  const float4* s0 = (const float4*)(out_ + (size_t)b * 6 * NPIX + 2 * (size_t)NPIX);
  const float4* s1 = (const float4*)(out_ + (size_t)b * 6 * NPIX + 3 * (size_t)NPIX);
  const float4* s2 = (const float4*)(out_ + (size_t)b * 6 * NPIX + 4 * (size_t)NPIX);
  const float4* s3 = (const float4*)(out_ + (size_t)b * 6 * NPIX + 5 * (size_t)NPIX);
  const int4* gt = (const int4*)(lab_ + (size_t)b * 2 * NPIX);
  const float4* tmv = (const float4*)(tm_ + (size_t)b * NPIX);

  float at = 0.f, bt = 0.f, ct = 0.f;
  // grid.x = 100 -> 25600 threads/batch, exactly 4 quad-iters each
#pragma unroll
  for (int it = 0; it < 4; ++it) {
    const int i = it * 25600 + blockIdx.x * 256 + tid;
    float4 t4 = tx[i], m4 = tmv[i];
    int4 g4 = gt[i];
    float4 a0 = s0[i], a1 = s1[i], a2 = s2[i], a3 = s3[i];
#pragma unroll
    for (int j = 0; j < 4; ++j) {
      float tv = ((const float*)&t4)[j];
      float mv = ((const float*)&m4)[j];
      int gtv = ((const int*)&g4)[j];
      bool pos = gtv > 0;
      float st = 1.f / (1.f + expf(-tv));
      float sel = fall ? mv : ((((tv >= th) || pos) && (mv > 0.5f)) ? 1.f : 0.f);
      float p = st * sel;
      float tt = pos ? sel : 0.f;
      at += p * tt; bt += p * p; ct += tt * tt;
      int idx = pos ? (gtv - 1) : 7;
      int kk = pos ? gtv : 0;
      float d0 = ((const float*)&a0)[j] - sG[kk * 4 + 0];
      float d1 = ((const float*)&a1)[j] - sG[kk * 4 + 1];
      float d2 = ((const float*)&a2)[j] - sG[kk * 4 + 2];
      float d3 = ((const float*)&a3)[j] - sG[kk * 4 + 3];
      float sq = d0 * d0 + d1 * d1 + d2 * d2 + d3 * d3;
      float d = (sq > 0.f) ? sqrtf(sq) : 0.f;
      float dd = fmaxf(d - 0.5f, 0.f);
      float lg = pos ? log1pf(dd * dd) : 0.f;
      LA[idx * 257 + tid] += lg;
    }
  }

  float f;
  f = wredf(at); if (lane == 0) sWred[w * 3 + 0] = f;
  f = wredf(bt); if (lane == 0) sWred[w * 3 + 1] = f;
  f = wredf(ct); if (lane == 0) sWred[w * 3 + 2] = f;
  __syncthreads();
  {
    int p = tid & 7, sub = tid >> 3;
    float part = 0.f;
#pragma unroll
    for (int i = 0; i < 8; ++i) part += LA[p * 257 + (sub + 32 * i)];
    L2[p * 33 + sub] = part;
  }
  __syncthreads();
  if (tid < 7) {
    float s = 0.f;
#pragma unroll
    for (int q = 0; q < 32; ++q) s += L2[tid * 33 + q];
    if (s != 0.f) atomicAdd(&wsbf[OFF_AGG + 1 + tid], s);
  } else if (tid >= 32 && tid < 35) {
    int c = tid - 32;
    float s = sWred[c] + sWred[3 + c] + sWred[6 + c] + sWred[9 + c];
    atomicAdd(&wsbf[OFF_DICE + c], s);
  }
}

// ---- pass H: finalize 5 scalars ---------------------------------------------
__global__ void kH(const unsigned* __restrict__ ws, float* __restrict__ out) {
  __shared__ float sv[4][8];
  const int b = threadIdx.x;
  if (b < 8) {
    const unsigned* wsb = ws + (size_t)b * PER_BATCH;
    const float* wsbf = (const float*)wsb;
    float at = wsbf[OFF_DICE + 0], bt = wsbf[OFF_DICE + 1] + 1e-3f, ct = wsbf[OFF_DICE + 2] + 1e-3f;
    float lt = 1.f - 2.f * at / (bt + ct);
    float ak = wsbf[OFF_DICE + 3], bk = wsbf[OFF_DICE + 4] + 1e-3f, ck = wsbf[OFF_DICE + 5] + 1e-3f;
    float lk = 1.f - 2.f * ak / (bk + ck);
    unsigned vm = wsb[OFF_VM], nvv = wsb[OFF_NV];
    float s = 0.f;
    for (int k = 1; k < 8; ++k)
      if ((vm >> k) & 1) s += wsbf[OFF_AGG + k] / fmaxf((float)wsb[OFF_TC + k], 1.f);
    float la = s / fmaxf((float)nvv, 1.f);
    float ld = wsbf[OFF_LDIS];
    sv[0][b] = lt; sv[1][b] = lk; sv[2][b] = la; sv[3][b] = ld;
  }
  __syncthreads();
  if (threadIdx.x == 0) {
    float mt = 0.f, mk = 0.f, ma = 0.f, md = 0.f;
    for (int i = 0; i < 8; ++i) { mt += sv[0][i]; mk += sv[1][i]; ma += sv[2][i]; md += sv[3][i]; }
    mt *= 0.125f; mk *= 0.125f; ma *= 0.125f; md *= 0.125f;
    out[0] = mt + 0.5f * mk + 0.25f * (ma + md);
    out[1] = mt;
    out[2] = mk;
    out[3] = ma;
    out[4] = md;
  }
}

extern "C" void kernel_launch(void* const* d_in, const int* in_sizes, int n_in,
                              void* d_out, int out_size, void* d_ws, size_t ws_size,
                              hipStream_t stream) {
  const float* outputs = (const float*)d_in[0];
  const int* labels = (const int*)d_in[1];
  const float* tm = (const float*)d_in[2];
  unsigned* ws = (unsigned*)d_ws;
  float* out = (float*)d_out;

  const bool compact = ws_size >= (size_t)(KEYS_BASE + (size_t)NB * NPIX) * 4;

  dim3 blk(256);
  kZ<<<(HDR_WORDS + 255) / 256, blk, 0, stream>>>(ws);
  if (compact) {
    kP1<true><<<dim3(200, NB), blk, 0, stream>>>(outputs, labels, tm, ws);
    kSel<<<NB, 1024, 0, stream>>>(ws);
  } else {
    kP1<false><<<dim3(200, NB), blk, 0, stream>>>(outputs, labels, tm, ws);
    kB<<<NB, 256, 0, stream>>>(ws);
    kC<<<dim3(128, NB), blk, 0, stream>>>(outputs, labels, ws);
    kD<<<NB, 256, 0, stream>>>(ws);
    kE<<<dim3(128, NB), blk, 0, stream>>>(outputs, labels, ws);
    kF<<<NB, 256, 0, stream>>>(ws);
  }
  kG<<<dim3(100, NB), blk, 0, stream>>>(outputs, labels, tm, ws);
  kH<<<1, 64, 0, stream>>>(ws, out);
}